// Round 2
// baseline (1037.261 us; speedup 1.0000x reference)
//
#include <hip/hip_runtime.h>
#include <math.h>

#define DIM    1024
#define INNER  2048
#define BATCH  32
#define WCHUNK 32    // colsum partial chunks per batch
#define CR     64    // rows per wsum block (INNER / WCHUNK)

__device__ __forceinline__ float4 f4add(float4 a, float4 b) {
    return make_float4(a.x + b.x, a.y + b.y, a.z + b.z, a.w + b.w);
}

__device__ __forceinline__ float hsum8(const float4* w) {
    float4 a = f4add(f4add(w[0], w[1]), f4add(w[2], w[3]));
    float4 b = f4add(f4add(w[4], w[5]), f4add(w[6], w[7]));
    float4 c = f4add(a, b);
    return (c.x + c.y) + (c.z + c.w);
}

// ---------------------------------------------------------------------------
// K1 (fused): blocks [0,1024): W pass 1 — colsum partials + rowsum.
//   No shuffle chains: each lane writes one per-row partial to LDS; block
//   reduce at the end. 2 rows/iter -> 16 float4 in flight per lane.
//   blocks [1024,1536): q/k/v GEMV overlapping the BW-bound W stream.
// ---------------------------------------------------------------------------
__global__ __launch_bounds__(256) void pre_kernel(
    const float* __restrict__ x,
    const float* __restrict__ Wq, const float* __restrict__ bq,
    const float* __restrict__ Wk, const float* __restrict__ bk,
    const float* __restrict__ Wv, const float* __restrict__ bv,
    const float* __restrict__ W,
    float* __restrict__ q, float* __restrict__ k, float* __restrict__ v,
    float* __restrict__ colpart, float* __restrict__ rowsum)
{
    __shared__ float  rowpart[CR][66];   // 16.9 KB, padded (2-way = free)
    __shared__ float4 csumsh[512];       // 8 KB; qkv path reuses as xs
    const int bid = blockIdx.x;
    const int t   = threadIdx.x;

    if (bid < BATCH * WCHUNK) {
        const int b     = bid & (BATCH - 1);   // b fastest in dispatch order
        const int chunk = bid >> 5;
        const int i0    = chunk * CR;
        const int wave  = t >> 6, lane = t & 63;
        const float4* Wp = (const float4*)(W + (size_t)b * INNER * INNER);

        float4 csum[8];
        #pragma unroll
        for (int c = 0; c < 8; ++c) csum[c] = make_float4(0.f, 0.f, 0.f, 0.f);

        // wave handles local rows 4*j + wave, two rows per iteration
        for (int j = 0; j < 16; j += 2) {
            const int ra = 4 * j + wave;
            const int rb = ra + 4;
            const size_t ba = (size_t)(i0 + ra) * (INNER / 4);
            const size_t bb = (size_t)(i0 + rb) * (INNER / 4);
            float4 wa[8], wb[8];
            #pragma unroll
            for (int c = 0; c < 8; ++c) wa[c] = Wp[ba + lane + 64 * c];
            #pragma unroll
            for (int c = 0; c < 8; ++c) wb[c] = Wp[bb + lane + 64 * c];
            #pragma unroll
            for (int c = 0; c < 8; ++c)
                csum[c] = f4add(csum[c], f4add(wa[c], wb[c]));
            rowpart[ra][lane] = hsum8(wa);
            rowpart[rb][lane] = hsum8(wb);
        }

        // combine per-wave column sums in LDS (round-robin, no atomics)
        for (int wv = 0; wv < 4; ++wv) {
            __syncthreads();
            if (wave == wv) {
                #pragma unroll
                for (int c = 0; c < 8; ++c) {
                    if (wv == 0) csumsh[lane + 64 * c] = csum[c];
                    else csumsh[lane + 64 * c] = f4add(csumsh[lane + 64 * c], csum[c]);
                }
            }
        }
        __syncthreads();

        float4* cp = (float4*)colpart + (size_t)(b * WCHUNK + chunk) * (INNER / 4);
        cp[t]       = csumsh[t];
        cp[t + 256] = csumsh[t + 256];

        if (t < 128) {          // 2 threads per row reduce 64 lane-partials
            const int r = t >> 1, half = t & 1;
            float s = 0.f;
            #pragma unroll
            for (int l = 0; l < 32; ++l) s += rowpart[r][half * 32 + l];
            s += __shfl_xor(s, 1, 64);
            if (half == 0) rowsum[b * INNER + i0 + r] = s;
        }
    } else {
        // ---- qkv GEMV ----
        const int idx = bid - BATCH * WCHUNK;
        const int b   = idx & (BATCH - 1);
        float* xs = (float*)csumsh;
        const float4* xsrc = (const float4*)(x + b * DIM);
        float4* xdst = (float4*)xs;
        for (int i = t; i < DIM / 4; i += 256) xdst[i] = xsrc[i];
        __syncthreads();

        const int c = (idx >> 5) * 256 + t;   // 0..4095: [q|k|v] virtual cols
        const float* Wm; const float* bias; float* outp; int N, n;
        if (c < DIM)          { Wm = Wq; bias = bq; outp = q; N = DIM;   n = c;           }
        else if (c < 2 * DIM) { Wm = Wk; bias = bk; outp = k; N = DIM;   n = c - DIM;     }
        else                  { Wm = Wv; bias = bv; outp = v; N = INNER; n = c - 2 * DIM; }

        float acc = 0.f;
        #pragma unroll 8
        for (int kk = 0; kk < DIM; ++kk)
            acc += xs[kk] * Wm[(size_t)kk * N + n];
        outp[(size_t)b * N + n] = acc + bias[n];
    }
}

// dpfp "concat(relu(k), relu(-k))" element (from an LDS-staged row)
__device__ __forceinline__ float xcf(const float* __restrict__ kb, int j) {
    float val = (j < DIM) ? kb[j] : -kb[j - DIM];
    return fmaxf(val, 0.f);
}

// ---------------------------------------------------------------------------
// K2: per-batch vector work + colsum partial reduction, fully float4.
// One block per b; thread t owns elements [4t,4t+4) and [1024+4t,1024+4t+4).
// ---------------------------------------------------------------------------
__global__ __launch_bounds__(256) void vec_kernel(
    const float* __restrict__ x, const float* __restrict__ Wb, const float* __restrict__ bb,
    const float* __restrict__ q, const float* __restrict__ k, const float* __restrict__ v,
    const float* __restrict__ colpart, const float* __restrict__ rowsum,
    float* __restrict__ kp, float* __restrict__ dv, float* __restrict__ outv)
{
    __shared__ float kb_s[DIM], qb_s[DIM];
    __shared__ float red1[4], red2[4];
    const int b = blockIdx.x, t = threadIdx.x;
    const int wave = t >> 6, lane = t & 63;

    ((float4*)kb_s)[t] = ((const float4*)(k + b * DIM))[t];
    ((float4*)qb_s)[t] = ((const float4*)(q + b * DIM))[t];
    const float* xrow = x + b * DIM;
    float bsum = 0.f;
    for (int i = t; i < DIM; i += 256) bsum += xrow[i] * Wb[i];
    #pragma unroll
    for (int m = 1; m < 64; m <<= 1) bsum += __shfl_xor(bsum, m, 64);
    if (lane == 0) red1[wave] = bsum;
    __syncthreads();
    const float beta = 1.f / (1.f + expf(-((red1[0] + red1[1] + red1[2] + red1[3]) + bb[0])));

    // colsum partial reduction (32 chunks), float4
    float4 cs_a = make_float4(0.f, 0.f, 0.f, 0.f);
    float4 cs_b = make_float4(0.f, 0.f, 0.f, 0.f);
    #pragma unroll 4
    for (int c = 0; c < WCHUNK; ++c) {
        const float4* cp = (const float4*)colpart + (size_t)(b * WCHUNK + c) * (INNER / 4);
        cs_a = f4add(cs_a, cp[t]);
        cs_b = f4add(cs_b, cp[t + 256]);
    }

    const int ja = 4 * t, jb = DIM + 4 * t;
    float kpa[4], kpb[4], skp = 0.f;
    #pragma unroll
    for (int e = 0; e < 4; ++e) {
        kpa[e] = xcf(kb_s, ja + e) * xcf(kb_s, (ja + e + INNER - 1) & (INNER - 1));
        kpb[e] = xcf(kb_s, jb + e) * xcf(kb_s, (jb + e + INNER - 1) & (INNER - 1));
        skp += kpa[e] + kpb[e];
    }
    ((float4*)(kp + b * INNER))[t]       = make_float4(kpa[0], kpa[1], kpa[2], kpa[3]);
    ((float4*)(kp + b * INNER))[t + 256] = make_float4(kpb[0], kpb[1], kpb[2], kpb[3]);

    const float4 v_a = ((const float4*)(v + b * INNER))[t];
    const float4 v_b = ((const float4*)(v + b * INNER))[t + 256];
    float4 dva, dvb;
    dva.x = beta * (v_a.x - cs_a.x * kpa[0]); dva.y = beta * (v_a.y - cs_a.y * kpa[1]);
    dva.z = beta * (v_a.z - cs_a.z * kpa[2]); dva.w = beta * (v_a.w - cs_a.w * kpa[3]);
    dvb.x = beta * (v_b.x - cs_b.x * kpb[0]); dvb.y = beta * (v_b.y - cs_b.y * kpb[1]);
    dvb.z = beta * (v_b.z - cs_b.z * kpb[2]); dvb.w = beta * (v_b.w - cs_b.w * kpb[3]);
    ((float4*)(dv + b * INNER))[t]       = dva;
    ((float4*)(dv + b * INNER))[t + 256] = dvb;

    #pragma unroll
    for (int m = 1; m < 64; m <<= 1) skp += __shfl_xor(skp, m, 64);
    if (lane == 0) red2[wave] = skp;
    __syncthreads();
    const float S = red2[0] + red2[1] + red2[2] + red2[3];

    const float4 ru_a = ((const float4*)(rowsum + b * INNER))[t];
    const float4 ru_b = ((const float4*)(rowsum + b * INNER))[t + 256];
    float4 oa, ob;
    oa.x = (ru_a.x + dva.x * S) * (xcf(qb_s, ja + 0) * xcf(qb_s, (ja + 0 + INNER - 1) & (INNER - 1)));
    oa.y = (ru_a.y + dva.y * S) * (xcf(qb_s, ja + 1) * xcf(qb_s, (ja + 1 + INNER - 1) & (INNER - 1)));
    oa.z = (ru_a.z + dva.z * S) * (xcf(qb_s, ja + 2) * xcf(qb_s, (ja + 2 + INNER - 1) & (INNER - 1)));
    oa.w = (ru_a.w + dva.w * S) * (xcf(qb_s, ja + 3) * xcf(qb_s, (ja + 3 + INNER - 1) & (INNER - 1)));
    ob.x = (ru_b.x + dvb.x * S) * (xcf(qb_s, jb + 0) * xcf(qb_s, (jb + 0 + INNER - 1) & (INNER - 1)));
    ob.y = (ru_b.y + dvb.y * S) * (xcf(qb_s, jb + 1) * xcf(qb_s, (jb + 1 + INNER - 1) & (INNER - 1)));
    ob.z = (ru_b.z + dvb.z * S) * (xcf(qb_s, jb + 2) * xcf(qb_s, (jb + 2 + INNER - 1) & (INNER - 1)));
    ob.w = (ru_b.w + dvb.w * S) * (xcf(qb_s, jb + 3) * xcf(qb_s, (jb + 3 + INNER - 1) & (INNER - 1)));
    ((float4*)(outv + b * INNER))[t]       = oa;
    ((float4*)(outv + b * INNER))[t + 256] = ob;
}

// ---------------------------------------------------------------------------
// K3 (fused): blocks [0,512): out = outv @ Wo + bo.
//   blocks [512,512+16384): Wn update, 4 rows/block in REVERSE row order —
//   first blocks touch the W rows pre_kernel read last -> Infinity-Cache hits
//   on up to ~256 MB of the re-read. kp row loaded once, reused across 4 rows.
// ---------------------------------------------------------------------------
__global__ __launch_bounds__(256) void post_kernel(
    const float* __restrict__ outv, const float* __restrict__ Wo,
    const float* __restrict__ bo, float* __restrict__ out,
    const float* __restrict__ W, const float* __restrict__ dv,
    const float* __restrict__ kp, float* __restrict__ Wn)
{
    const int bid = blockIdx.x;
    const int t   = threadIdx.x;
    if (bid < 512) {
        __shared__ float os[INNER];
        __shared__ float part[4][64];
        const int b    = bid & (BATCH - 1);
        const int n0   = (bid >> 5) * 64;
        const int wave = t >> 6, lane = t & 63;

        const float4* src = (const float4*)(outv + b * INNER);
        float4* dst = (float4*)os;
        for (int i = t; i < INNER / 4; i += 256) dst[i] = src[i];
        __syncthreads();

        const float* Wcol = Wo + n0 + lane;
        const int ibase = wave * 512;
        float acc = 0.f;
        #pragma unroll 8
        for (int i = 0; i < 512; ++i)
            acc += os[ibase + i] * Wcol[(size_t)(ibase + i) * DIM];
        part[wave][lane] = acc;
        __syncthreads();
        if (t < 64)
            out[b * DIM + n0 + t] =
                ((part[0][t] + part[1][t]) + (part[2][t] + part[3][t])) + bo[n0 + t];
    } else {
        const int idx = bid - 512;                       // 0..16383
        const int blk = (BATCH * (INNER / 4) - 1) - idx; // reversed
        const int b   = blk >> 9;
        const int r0  = (blk & 511) << 2;                // first of 4 rows

        const float4* kp4 = (const float4*)(kp + (size_t)b * INNER);
        const float4 k0 = kp4[t], k1 = kp4[t + 256];

        const float* dvb = dv + (size_t)b * INNER + r0;
        float dloc[4];
        #pragma unroll
        for (int r = 0; r < 4; ++r) dloc[r] = dvb[r];

        const size_t rowbase = (size_t)(b * INNER + r0) * (INNER / 4);
        const float4* Wb4 = (const float4*)W + rowbase;
        float4*       Wn4 = (float4*)Wn + rowbase;

        float4 w[8];
        #pragma unroll
        for (int r = 0; r < 4; ++r) {
            w[2 * r]     = Wb4[(size_t)r * (INNER / 4) + t];
            w[2 * r + 1] = Wb4[(size_t)r * (INNER / 4) + t + 256];
        }
        #pragma unroll
        for (int r = 0; r < 4; ++r) {
            const float d = dloc[r];
            float4 a = w[2 * r], c = w[2 * r + 1];
            a.x += d * k0.x; a.y += d * k0.y; a.z += d * k0.z; a.w += d * k0.w;
            c.x += d * k1.x; c.y += d * k1.y; c.z += d * k1.z; c.w += d * k1.w;
            Wn4[(size_t)r * (INNER / 4) + t]       = a;
            Wn4[(size_t)r * (INNER / 4) + t + 256] = c;
        }
    }
}

// ---------------------------------------------------------------------------
extern "C" void kernel_launch(void* const* d_in, const int* in_sizes, int n_in,
                              void* d_out, int out_size, void* d_ws, size_t ws_size,
                              hipStream_t stream)
{
    const float* x  = (const float*)d_in[0];
    const float* W  = (const float*)d_in[1];
    const float* Wq = (const float*)d_in[2];
    const float* bq = (const float*)d_in[3];
    const float* Wk = (const float*)d_in[4];
    const float* bk = (const float*)d_in[5];
    const float* Wv = (const float*)d_in[6];
    const float* bv = (const float*)d_in[7];
    const float* Wo = (const float*)d_in[8];
    const float* bo = (const float*)d_in[9];
    const float* Wb = (const float*)d_in[10];
    const float* bb = (const float*)d_in[11];

    float* out = (float*)d_out;                          // [32,1024]
    float* Wn  = (float*)d_out + (size_t)BATCH * DIM;    // [32,2048,2048]

    float* ws = (float*)d_ws;
    float* q       = ws;                        // 32*1024
    float* k       = q + BATCH * DIM;           // 32*1024
    float* v       = k + BATCH * DIM;           // 32*2048
    float* rowsum  = v + BATCH * INNER;         // 32*2048
    float* kp      = rowsum + BATCH * INNER;    // 32*2048
    float* dv      = kp + BATCH * INNER;        // 32*2048
    float* outv    = dv + BATCH * INNER;        // 32*2048
    float* colpart = outv + BATCH * INNER;      // 32*32*2048 = 8 MB

    pre_kernel<<<dim3(BATCH * WCHUNK + 512), 256, 0, stream>>>(
        x, Wq, bq, Wk, bk, Wv, bv, W, q, k, v, colpart, rowsum);
    vec_kernel<<<dim3(BATCH), 256, 0, stream>>>(
        x, Wb, bb, q, k, v, colpart, rowsum, kp, dv, outv);
    post_kernel<<<dim3(512 + BATCH * (INNER / 4)), 256, 0, stream>>>(
        outv, Wo, bo, out, W, dv, kp, Wn);
}